// Round 1
// baseline (1193.160 us; speedup 1.0000x reference)
//
#include <hip/hip_runtime.h>
#include <hip/hip_bf16.h>

// Problem constants (fixed by reference):
//   B=8, C=32, H=W=32 -> Ho=Wo=16, N=Ho*Wo=256, HW=H*W=1024
//   mu_in   : [B,C,H,W]        f32
//   Sigma_in: [B,C,HW,HW]      f32
//   out     : mu_out [B,C,Ho,Wo] (65536 f32)  ++  Sigma_out [B,C,N,N] (16777216 f32)

#define BC    256        // B*C
#define H     32
#define W     32
#define HO    16
#define WO    16
#define NPOOL 256        // HO*WO
#define HW    1024       // H*W

// Kernel 1: 2x2 max pool with argmax flat indices.
// grid = BC blocks, 256 threads; thread t handles pooled pixel n=t of image bc.
__global__ void pool_idx_kernel(const float* __restrict__ mu_in,
                                float* __restrict__ mu_out,
                                int* __restrict__ idx_ws) {
    const int bc = blockIdx.x;          // 0..255
    const int n  = threadIdx.x;         // 0..255
    const int i  = n >> 4;              // pooled row 0..15
    const int j  = n & 15;              // pooled col 0..15

    const float* img = mu_in + (size_t)bc * (H * W);
    const int r0 = 2 * i, c0 = 2 * j;

    // window order w = kh*2 + kw (matches jnp.argmax first-occurrence)
    float v0 = img[(r0    ) * W + c0    ];
    float v1 = img[(r0    ) * W + c0 + 1];
    float v2 = img[(r0 + 1) * W + c0    ];
    float v3 = img[(r0 + 1) * W + c0 + 1];

    float best = v0; int w = 0;
    if (v1 > best) { best = v1; w = 1; }
    if (v2 > best) { best = v2; w = 2; }
    if (v3 > best) { best = v3; w = 3; }

    const int row = r0 + (w >> 1);
    const int col = c0 + (w & 1);
    const int flat = row * W + col;     // 0..1023

    mu_out[(size_t)bc * NPOOL + n] = best;
    idx_ws[bc * NPOOL + n] = flat;
}

// Kernel 2: double gather.
// grid.x = BC * NPOOL (one block per output row), 256 threads (one per column j).
__global__ void sigma_gather_kernel(const float* __restrict__ Sigma_in,
                                    const int* __restrict__ idx_ws,
                                    float* __restrict__ Sigma_out) {
    const int blk = blockIdx.x;
    const int bc  = blk >> 8;           // 0..255
    const int i   = blk & 255;          // output row 0..255
    const int j   = threadIdx.x;        // output col 0..255

    const int* idx = idx_ws + bc * NPOOL;
    const int r  = idx[i];              // wave-uniform broadcast load
    const int cj = idx[j];              // coalesced 256-int load

    const float* srow = Sigma_in + (size_t)bc * HW * HW + (size_t)r * HW;
    const float  v    = srow[cj];

    Sigma_out[(size_t)bc * (NPOOL * NPOOL) + (size_t)i * NPOOL + j] = v;
}

extern "C" void kernel_launch(void* const* d_in, const int* in_sizes, int n_in,
                              void* d_out, int out_size, void* d_ws, size_t ws_size,
                              hipStream_t stream) {
    const float* mu_in    = (const float*)d_in[0];
    const float* Sigma_in = (const float*)d_in[1];

    float* mu_out    = (float*)d_out;                 // 65536 floats
    float* Sigma_out = (float*)d_out + BC * NPOOL;    // 16777216 floats
    int*   idx_ws    = (int*)d_ws;                    // 256*256 ints = 256 KiB

    pool_idx_kernel<<<BC, NPOOL, 0, stream>>>(mu_in, mu_out, idx_ws);
    sigma_gather_kernel<<<BC * NPOOL, NPOOL, 0, stream>>>(Sigma_in, idx_ws, Sigma_out);
}